// Round 1
// baseline (566.685 us; speedup 1.0000x reference)
//
#include <hip/hip_runtime.h>
#include <hip/hip_bf16.h>
#include <stdint.h>

// Problem constants
#define NS 32          // samples
#define NA 512         // atoms
#define IND 64         // in_depth
#define OD 64          // out_depth
#define FL 12          // filter_length
#define KTOT (NA*FL)   // 6144 contraction length (k = n*12 + f)
#define WROW 66        // filters innermost dim (in_depth+2)

typedef __bf16 bf16x8 __attribute__((ext_vector_type(8)));
typedef float  f32x4  __attribute__((ext_vector_type(4)));

// ---------------------------------------------------------------------------
// Kernel 1: Gt[s][o][n*12+f] = sum_d node[s][n][d] * W[o][f][d]   (bf16 store)
// One block per (s,o). W[o] slice staged in LDS (broadcast reads), node row
// held in registers, 24 contiguous bf16 outputs per thread (coalesced uint4).
// ---------------------------------------------------------------------------
__global__ __launch_bounds__(256, 4)
void k_prep(const float* __restrict__ node, const float* __restrict__ W,
            __bf16* __restrict__ gt) {
    const int bid = blockIdx.x;
    const int s = bid >> 6;
    const int o = bid & 63;
    const int tid = threadIdx.x;

    __shared__ float Wl[FL * IND];                 // packed [f][d], stride 64
    for (int i = tid; i < FL * IND; i += 256) {
        const int f = i >> 6, d = i & 63;
        Wl[i] = W[(size_t)o * (FL * WROW) + f * WROW + d];
    }
    __syncthreads();
    const f32x4* w4 = reinterpret_cast<const f32x4*>(Wl);   // [f*16 + j]

    alignas(16) __bf16 buf[24];
    #pragma unroll
    for (int nn = 0; nn < 2; ++nn) {
        const int n = tid * 2 + nn;
        const f32x4* nr = reinterpret_cast<const f32x4*>(node + ((size_t)s * NA + n) * IND);
        f32x4 nv[16];
        #pragma unroll
        for (int j = 0; j < 16; ++j) nv[j] = nr[j];
        #pragma unroll
        for (int f = 0; f < FL; ++f) {
            f32x4 a = {0.f, 0.f, 0.f, 0.f};
            #pragma unroll
            for (int j = 0; j < 16; ++j) a += nv[j] * w4[f * 16 + j];
            buf[nn * FL + f] = (__bf16)(a.x + a.y + a.z + a.w);
        }
    }
    // 24 contiguous bf16 (48 B, 16B-aligned) at k = tid*24
    uint4* dst = reinterpret_cast<uint4*>(gt + ((size_t)s * OD + o) * KTOT + (size_t)tid * 24);
    const uint4* src = reinterpret_cast<const uint4*>(buf);
    dst[0] = src[0]; dst[1] = src[1]; dst[2] = src[2];
}

// ---------------------------------------------------------------------------
// Kernel 2: out[s][a][o] = sum_k conn[s][a][k] * Gt[s][o][k]  + bond term.
// Block = (s, 16-row a-tile). 8 waves split K (768 each), LDS reduce, fused
// bond epilogue. bid = at*32 + s so a sample's blocks share an XCD (L2 reuse
// of Gt[s]).
// mfma_f32_16x16x32_bf16 fragments: A/B row|col = lane&15, k = 8*(lane>>4)+j
// (8 contiguous k -> one 16B load); D: col = lane&15, row = 4*(lane>>4)+reg.
// ---------------------------------------------------------------------------
__global__ __launch_bounds__(512, 4)
void k_main(const float* __restrict__ conn, const __bf16* __restrict__ gt,
            const float* __restrict__ bond, const float* __restrict__ W,
            float* __restrict__ out) {
    const int bid = blockIdx.x;
    const int s  = bid & 31;          // bid % 8 == s % 8  -> XCD grouping
    const int at = bid >> 5;          // 0..31
    const int a0 = at << 4;
    const int tid = threadIdx.x;
    const int w  = tid >> 6;          // wave id = K-quarter (0..7)
    const int l  = tid & 63;
    const int lr = l & 15;
    const int lg = l >> 4;
    const int kbase = w * (KTOT / 8) + lg * 8;

    const float*  ap  = conn + ((size_t)s * NA + a0 + lr) * KTOT + kbase;
    const __bf16* bp0 = gt   + ((size_t)s * OD + lr) * KTOT + kbase;
    const __bf16* bp1 = bp0 + (size_t)16 * KTOT;
    const __bf16* bp2 = bp0 + (size_t)32 * KTOT;
    const __bf16* bp3 = bp0 + (size_t)48 * KTOT;

    f32x4 acc0 = {0.f,0.f,0.f,0.f}, acc1 = {0.f,0.f,0.f,0.f};
    f32x4 acc2 = {0.f,0.f,0.f,0.f}, acc3 = {0.f,0.f,0.f,0.f};

    for (int i = 0; i < (KTOT / 8) / 32; ++i) {   // 24 iterations, K=32 each
        const f32x4 alo = *reinterpret_cast<const f32x4*>(ap);
        const f32x4 ahi = *reinterpret_cast<const f32x4*>(ap + 4);
        bf16x8 av;
        av[0] = (__bf16)alo.x; av[1] = (__bf16)alo.y;
        av[2] = (__bf16)alo.z; av[3] = (__bf16)alo.w;
        av[4] = (__bf16)ahi.x; av[5] = (__bf16)ahi.y;
        av[6] = (__bf16)ahi.z; av[7] = (__bf16)ahi.w;
        const bf16x8 bv0 = *reinterpret_cast<const bf16x8*>(bp0);
        const bf16x8 bv1 = *reinterpret_cast<const bf16x8*>(bp1);
        const bf16x8 bv2 = *reinterpret_cast<const bf16x8*>(bp2);
        const bf16x8 bv3 = *reinterpret_cast<const bf16x8*>(bp3);
        acc0 = __builtin_amdgcn_mfma_f32_16x16x32_bf16(av, bv0, acc0, 0, 0, 0);
        acc1 = __builtin_amdgcn_mfma_f32_16x16x32_bf16(av, bv1, acc1, 0, 0, 0);
        acc2 = __builtin_amdgcn_mfma_f32_16x16x32_bf16(av, bv2, acc2, 0, 0, 0);
        acc3 = __builtin_amdgcn_mfma_f32_16x16x32_bf16(av, bv3, acc3, 0, 0, 0);
        ap += 32; bp0 += 32; bp1 += 32; bp2 += 32; bp3 += 32;
    }

    // K-split reduce through LDS
    __shared__ float red[8][16][64];
    #pragma unroll
    for (int r = 0; r < 4; ++r) {
        red[w][lg * 4 + r][ 0 + lr] = acc0[r];
        red[w][lg * 4 + r][16 + lr] = acc1[r];
        red[w][lg * 4 + r][32 + lr] = acc2[r];
        red[w][lg * 4 + r][48 + lr] = acc3[r];
    }
    __syncthreads();

    #pragma unroll
    for (int p = 0; p < 2; ++p) {
        const int e = tid + p * 512;
        const int r = e >> 6, c = e & 63;
        float sum = 0.f;
        #pragma unroll
        for (int q = 0; q < 8; ++q) sum += red[q][r][c];
        const int a = a0 + r;
        const float* bb = bond + ((size_t)s * NA + a) * (FL * 2);
        const float* wb = W + (size_t)c * (FL * WROW) + IND;
        #pragma unroll
        for (int f = 0; f < FL; ++f)
            sum += bb[2 * f] * wb[f * WROW] + bb[2 * f + 1] * wb[f * WROW + 1];
        out[((size_t)s * NA + a) * OD + c] = sum;
    }
}

extern "C" void kernel_launch(void* const* d_in, const int* in_sizes, int n_in,
                              void* d_out, int out_size, void* d_ws, size_t ws_size,
                              hipStream_t stream) {
    const float* node = (const float*)d_in[0];
    const float* conn = (const float*)d_in[1];
    const float* bond = (const float*)d_in[2];
    const float* W    = (const float*)d_in[3];
    float* out = (float*)d_out;
    __bf16* gt = (__bf16*)d_ws;    // 32*64*6144 bf16 = 25.2 MB

    k_prep<<<dim3(NS * OD), dim3(256), 0, stream>>>(node, W, gt);
    k_main<<<dim3(NS * 32), dim3(512), 0, stream>>>(conn, gt, bond, W, out);
}

// Round 2
// 294.904 us; speedup vs baseline: 1.9216x; 1.9216x over previous
//
#include <hip/hip_runtime.h>
#include <hip/hip_bf16.h>
#include <stdint.h>

// Problem constants
#define NS 32          // samples
#define NA 512         // atoms
#define IND 64         // in_depth
#define OD 64          // out_depth
#define FL 12          // filter_length
#define KTOT (NA*FL)   // 6144 contraction length (k = n*12 + f)
#define WROW 66        // filters innermost dim (in_depth+2)

typedef __bf16 bf16x8 __attribute__((ext_vector_type(8)));
typedef float  f32x4  __attribute__((ext_vector_type(4)));

// ---------------------------------------------------------------------------
// Kernel 1 (v2): Gt[s][o][n*12+f] = sum_d node[s][n][d] * W[o][f][d]  (bf16)
// Block = (s, 64-atom chunk, o-group of 16). Node chunk staged coalesced in
// LDS, pulled into per-lane float nv[64] (all indices compile-time -> pure
// VGPR, no scratch). o is wave-uniform (readfirstlane) -> W reads are scalar
// s_load_dwordx16. Each lane writes 12 contiguous bf16 (24 B, lane-stride 24
// -> contiguous 1536 B per wave).
// ---------------------------------------------------------------------------
__global__ __launch_bounds__(256)
void k_prep(const float* __restrict__ node, const float* __restrict__ W,
            __bf16* __restrict__ gt) {
    const int bid = blockIdx.x;
    const int s  = bid >> 5;          // 0..31
    const int ac = (bid >> 2) & 7;    // 0..7  atom chunk
    const int og = bid & 3;           // 0..3  o-group
    const int a0 = ac << 6;
    const int tid = threadIdx.x;
    const int l  = tid & 63;

    __shared__ float nl[64][68];      // padded rows, 272 B stride (16B mult.)
    const f32x4* n4 = reinterpret_cast<const f32x4*>(node + ((size_t)s * NA + a0) * IND);
    #pragma unroll
    for (int it = 0; it < 4; ++it) {
        const int idx = tid + it * 256;       // 0..1023 f32x4 units
        const int row = idx >> 4, c4 = idx & 15;
        *reinterpret_cast<f32x4*>(&nl[row][c4 * 4]) = n4[idx];
    }
    __syncthreads();

    float nv[64];                     // lane's atom row, static-indexed only
    #pragma unroll
    for (int j = 0; j < 16; ++j)
        *reinterpret_cast<f32x4*>(&nv[4 * j]) =
            *reinterpret_cast<const f32x4*>(&nl[l][4 * j]);

    const int wv = __builtin_amdgcn_readfirstlane(tid >> 6);   // wave id 0..3

    for (int oi = 0; oi < 4; ++oi) {                  // runtime loop: o uniform
        const int o = og * 16 + wv * 4 + oi;
        const float* wb = W + (size_t)o * (FL * WROW);
        float acc[FL];
        #pragma unroll
        for (int f = 0; f < FL; ++f) {
            const float* wf = wb + f * WROW;          // 64 contiguous floats
            float p0 = 0.f, p1 = 0.f, p2 = 0.f, p3 = 0.f;
            #pragma unroll
            for (int d = 0; d < 64; d += 4) {
                p0 += nv[d]     * wf[d];
                p1 += nv[d + 1] * wf[d + 1];
                p2 += nv[d + 2] * wf[d + 2];
                p3 += nv[d + 3] * wf[d + 3];
            }
            acc[f] = (p0 + p1) + (p2 + p3);
        }
        alignas(8) __bf16 ob[FL];
        #pragma unroll
        for (int f = 0; f < FL; ++f) ob[f] = (__bf16)acc[f];
        uint2* dst = reinterpret_cast<uint2*>(
            gt + ((size_t)s * OD + o) * KTOT + (size_t)(a0 + l) * FL);
        const uint2* src = reinterpret_cast<const uint2*>(ob);
        dst[0] = src[0]; dst[1] = src[1]; dst[2] = src[2];
    }
}

// ---------------------------------------------------------------------------
// Kernel 2 (unchanged): out[s][a][o] = sum_k conn[s][a][k]*Gt[s][o][k] + bond.
// Block = (s, 16-row a-tile). 8 waves split K (768 each), LDS reduce, fused
// bond epilogue. bid = at*32 + s so a sample's blocks share an XCD (L2 reuse
// of Gt[s]).
// ---------------------------------------------------------------------------
__global__ __launch_bounds__(512, 4)
void k_main(const float* __restrict__ conn, const __bf16* __restrict__ gt,
            const float* __restrict__ bond, const float* __restrict__ W,
            float* __restrict__ out) {
    const int bid = blockIdx.x;
    const int s  = bid & 31;          // bid % 8 == s % 8  -> XCD grouping
    const int at = bid >> 5;          // 0..31
    const int a0 = at << 4;
    const int tid = threadIdx.x;
    const int w  = tid >> 6;          // wave id = K-eighth (0..7)
    const int l  = tid & 63;
    const int lr = l & 15;
    const int lg = l >> 4;
    const int kbase = w * (KTOT / 8) + lg * 8;

    const float*  ap  = conn + ((size_t)s * NA + a0 + lr) * KTOT + kbase;
    const __bf16* bp0 = gt   + ((size_t)s * OD + lr) * KTOT + kbase;
    const __bf16* bp1 = bp0 + (size_t)16 * KTOT;
    const __bf16* bp2 = bp0 + (size_t)32 * KTOT;
    const __bf16* bp3 = bp0 + (size_t)48 * KTOT;

    f32x4 acc0 = {0.f,0.f,0.f,0.f}, acc1 = {0.f,0.f,0.f,0.f};
    f32x4 acc2 = {0.f,0.f,0.f,0.f}, acc3 = {0.f,0.f,0.f,0.f};

    for (int i = 0; i < (KTOT / 8) / 32; ++i) {   // 24 iterations, K=32 each
        const f32x4 alo = *reinterpret_cast<const f32x4*>(ap);
        const f32x4 ahi = *reinterpret_cast<const f32x4*>(ap + 4);
        bf16x8 av;
        av[0] = (__bf16)alo.x; av[1] = (__bf16)alo.y;
        av[2] = (__bf16)alo.z; av[3] = (__bf16)alo.w;
        av[4] = (__bf16)ahi.x; av[5] = (__bf16)ahi.y;
        av[6] = (__bf16)ahi.z; av[7] = (__bf16)ahi.w;
        const bf16x8 bv0 = *reinterpret_cast<const bf16x8*>(bp0);
        const bf16x8 bv1 = *reinterpret_cast<const bf16x8*>(bp1);
        const bf16x8 bv2 = *reinterpret_cast<const bf16x8*>(bp2);
        const bf16x8 bv3 = *reinterpret_cast<const bf16x8*>(bp3);
        acc0 = __builtin_amdgcn_mfma_f32_16x16x32_bf16(av, bv0, acc0, 0, 0, 0);
        acc1 = __builtin_amdgcn_mfma_f32_16x16x32_bf16(av, bv1, acc1, 0, 0, 0);
        acc2 = __builtin_amdgcn_mfma_f32_16x16x32_bf16(av, bv2, acc2, 0, 0, 0);
        acc3 = __builtin_amdgcn_mfma_f32_16x16x32_bf16(av, bv3, acc3, 0, 0, 0);
        ap += 32; bp0 += 32; bp1 += 32; bp2 += 32; bp3 += 32;
    }

    // K-split reduce through LDS
    __shared__ float red[8][16][64];
    #pragma unroll
    for (int r = 0; r < 4; ++r) {
        red[w][lg * 4 + r][ 0 + lr] = acc0[r];
        red[w][lg * 4 + r][16 + lr] = acc1[r];
        red[w][lg * 4 + r][32 + lr] = acc2[r];
        red[w][lg * 4 + r][48 + lr] = acc3[r];
    }
    __syncthreads();

    #pragma unroll
    for (int p = 0; p < 2; ++p) {
        const int e = tid + p * 512;
        const int r = e >> 6, c = e & 63;
        float sum = 0.f;
        #pragma unroll
        for (int q = 0; q < 8; ++q) sum += red[q][r][c];
        const int a = a0 + r;
        const float* bb = bond + ((size_t)s * NA + a) * (FL * 2);
        const float* wb = W + (size_t)c * (FL * WROW) + IND;
        #pragma unroll
        for (int f = 0; f < FL; ++f)
            sum += bb[2 * f] * wb[f * WROW] + bb[2 * f + 1] * wb[f * WROW + 1];
        out[((size_t)s * NA + a) * OD + c] = sum;
    }
}

extern "C" void kernel_launch(void* const* d_in, const int* in_sizes, int n_in,
                              void* d_out, int out_size, void* d_ws, size_t ws_size,
                              hipStream_t stream) {
    const float* node = (const float*)d_in[0];
    const float* conn = (const float*)d_in[1];
    const float* bond = (const float*)d_in[2];
    const float* W    = (const float*)d_in[3];
    float* out = (float*)d_out;
    __bf16* gt = (__bf16*)d_ws;    // 32*64*6144 bf16 = 25.2 MB

    k_prep<<<dim3(NS * 32), dim3(256), 0, stream>>>(node, W, gt);
    k_main<<<dim3(NS * 32), dim3(512), 0, stream>>>(conn, gt, bond, W, out);
}

// Round 3
// 207.650 us; speedup vs baseline: 2.7290x; 1.4202x over previous
//
#include <hip/hip_runtime.h>
#include <hip/hip_bf16.h>
#include <stdint.h>

// Problem constants
#define NS 32          // samples
#define NA 512         // atoms
#define IND 64         // in_depth
#define OD 64          // out_depth
#define FL 12          // filter_length
#define KTOT (NA*FL)   // 6144 contraction length (k = n*12 + f)
#define WROW 66        // filters innermost dim (in_depth+2)

typedef __bf16 bf16x8 __attribute__((ext_vector_type(8)));
typedef float  f32x4  __attribute__((ext_vector_type(4)));

// ---------------------------------------------------------------------------
// Kernel 1: Gt[s][o][n*12+f] = sum_d node[s][n][d] * W[o][f][d]  (bf16)
// Same math as round 2 (passed), 2x block parallelism: 2 o per wave.
// ---------------------------------------------------------------------------
__global__ __launch_bounds__(256)
void k_prep(const float* __restrict__ node, const float* __restrict__ W,
            __bf16* __restrict__ gt) {
    const int bid = blockIdx.x;
    const int s  = bid >> 6;          // 0..31
    const int ac = (bid >> 3) & 7;    // 0..7  atom chunk
    const int og = bid & 7;           // 0..7  o-group (8 o each)
    const int a0 = ac << 6;
    const int tid = threadIdx.x;
    const int l  = tid & 63;

    __shared__ float nl[64][68];
    const f32x4* n4 = reinterpret_cast<const f32x4*>(node + ((size_t)s * NA + a0) * IND);
    #pragma unroll
    for (int it = 0; it < 4; ++it) {
        const int idx = tid + it * 256;
        const int row = idx >> 4, c4 = idx & 15;
        *reinterpret_cast<f32x4*>(&nl[row][c4 * 4]) = n4[idx];
    }
    __syncthreads();

    float nv[64];
    #pragma unroll
    for (int j = 0; j < 16; ++j)
        *reinterpret_cast<f32x4*>(&nv[4 * j]) =
            *reinterpret_cast<const f32x4*>(&nl[l][4 * j]);

    const int wv = __builtin_amdgcn_readfirstlane(tid >> 6);   // wave id 0..3

    for (int oi = 0; oi < 2; ++oi) {                  // o wave-uniform
        const int o = og * 8 + wv * 2 + oi;
        const float* wb = W + (size_t)o * (FL * WROW);
        float acc[FL];
        #pragma unroll
        for (int f = 0; f < FL; ++f) {
            const float* wf = wb + f * WROW;
            float p0 = 0.f, p1 = 0.f, p2 = 0.f, p3 = 0.f;
            #pragma unroll
            for (int d = 0; d < 64; d += 4) {
                p0 += nv[d]     * wf[d];
                p1 += nv[d + 1] * wf[d + 1];
                p2 += nv[d + 2] * wf[d + 2];
                p3 += nv[d + 3] * wf[d + 3];
            }
            acc[f] = (p0 + p1) + (p2 + p3);
        }
        alignas(8) __bf16 ob[FL];
        #pragma unroll
        for (int f = 0; f < FL; ++f) ob[f] = (__bf16)acc[f];
        uint2* dst = reinterpret_cast<uint2*>(
            gt + ((size_t)s * OD + o) * KTOT + (size_t)(a0 + l) * FL);
        const uint2* src = reinterpret_cast<const uint2*>(ob);
        dst[0] = src[0]; dst[1] = src[1]; dst[2] = src[2];
    }
}

// ---------------------------------------------------------------------------
// Kernel 2: out[s][a][o] = bond-term (base value for k_main's atomicAdd).
// Block = 4 atoms x 64 o. Writes ALL out elements (out is poisoned).
// ---------------------------------------------------------------------------
__global__ __launch_bounds__(256)
void k_init(const float* __restrict__ bond, const float* __restrict__ W,
            float* __restrict__ out) {
    const int bid = blockIdx.x;       // sa-group: atoms [bid*4, bid*4+4)
    const int tid = threadIdx.x;

    __shared__ float Wb[64][25];      // [o][f*2+c], padded (24->25) vs bank conflicts
    for (int i = tid; i < 64 * 24; i += 256) {
        const int o = i / 24, fc = i % 24;
        const int f = fc >> 1, c = fc & 1;
        Wb[o][fc] = W[(size_t)o * (FL * WROW) + f * WROW + IND + c];
    }
    __shared__ float bl[4][24];
    if (tid < 96) {
        const int a = tid / 24, fc = tid % 24;
        bl[a][fc] = bond[(size_t)bid * 4 * (FL * 2) + a * (FL * 2) + fc];
    }
    __syncthreads();

    const int aL = tid >> 6, o = tid & 63;
    float sum = 0.f;
    #pragma unroll
    for (int f = 0; f < FL; ++f)
        sum += bl[aL][2 * f] * Wb[o][2 * f] + bl[aL][2 * f + 1] * Wb[o][2 * f + 1];
    out[((size_t)bid * 4 + aL) * OD + o] = sum;
}

// ---------------------------------------------------------------------------
// Kernel 3: LDS-staged MFMA GEMM. Per sample: C[512x64] += conn.Gt^T.
// Grid 1024 = 32 s x 8 a-tiles(BM=64) x 4 K-quarters; block 256 thr (4 waves,
// each 32x32 out). BK=64, double-buffered LDS, one-step register prefetch
// (loads for t+1 in flight across barrier+MFMA), XOR-swizzled LDS
// (byte ^= (row&7)<<4) so ds_read_b128 fragment reads are conflict-free.
// bid&31 = s keeps a sample's Gt on one XCD's L2.
// ---------------------------------------------------------------------------
__global__ __launch_bounds__(256, 4)
void k_main(const float* __restrict__ conn, const __bf16* __restrict__ gt,
            float* __restrict__ out) {
    const int bid = blockIdx.x;
    const int s  = bid & 31;
    const int x  = bid >> 5;
    const int at = x >> 2;            // 0..7
    const int kq = x & 3;             // 0..3
    const int a0 = at << 6;
    const int k00 = kq * (KTOT / 4);  // 1536-elem K slice, 24 steps of 64
    const int tid = threadIdx.x;
    const int w  = tid >> 6, l = tid & 63;
    const int lr = l & 15, lg = l >> 4;
    const int m0 = (w >> 1) << 5;     // wave row offset (0/32)
    const int n0 = (w & 1) << 5;      // wave col offset (0/32)

    __shared__ __align__(16) unsigned char Al[2][8192];   // 64 rows x 128 B
    __shared__ __align__(16) unsigned char Bl[2][8192];

    // staging: thread -> (row, 32-byte chunk)
    const int srow = tid >> 2;        // 0..63
    const int scol = tid & 3;         // 0..3
    const float*  aG = conn + ((size_t)s * NA + a0 + srow) * KTOT + k00 + scol * 16;
    const __bf16* bG = gt   + ((size_t)s * OD + srow)      * KTOT + k00 + scol * 16;
    const int wsw   = (srow & 7) << 4;
    const int woff0 = srow * 128 + ((scol * 32) ^ wsw);
    const int woff1 = srow * 128 + ((scol * 32 + 16) ^ wsw);

    f32x4 pa0, pa1, pa2, pa3;
    uint4 pb0, pb1;
    pa0 = *reinterpret_cast<const f32x4*>(aG);
    pa1 = *reinterpret_cast<const f32x4*>(aG + 4);
    pa2 = *reinterpret_cast<const f32x4*>(aG + 8);
    pa3 = *reinterpret_cast<const f32x4*>(aG + 12);
    pb0 = *reinterpret_cast<const uint4*>(bG);
    pb1 = *reinterpret_cast<const uint4*>(bG + 8);

    f32x4 acc00 = {0.f,0.f,0.f,0.f}, acc01 = {0.f,0.f,0.f,0.f};
    f32x4 acc10 = {0.f,0.f,0.f,0.f}, acc11 = {0.f,0.f,0.f,0.f};

    const int rsw = (lr & 7) << 4;                   // read-side swizzle
    const int rowA0 = (m0 + lr) * 128;               // mi=1 -> +2048
    const int rowB0 = (n0 + lr) * 128;               // ni=1 -> +2048

    #pragma unroll 2
    for (int t = 0; t < 24; ++t) {
        unsigned char* Ab = Al[t & 1];
        unsigned char* Bb = Bl[t & 1];
        // convert + write current step (vmcnt wait inserted here by compiler)
        bf16x8 wlo, whi;
        wlo[0] = (__bf16)pa0.x; wlo[1] = (__bf16)pa0.y;
        wlo[2] = (__bf16)pa0.z; wlo[3] = (__bf16)pa0.w;
        wlo[4] = (__bf16)pa1.x; wlo[5] = (__bf16)pa1.y;
        wlo[6] = (__bf16)pa1.z; wlo[7] = (__bf16)pa1.w;
        whi[0] = (__bf16)pa2.x; whi[1] = (__bf16)pa2.y;
        whi[2] = (__bf16)pa2.z; whi[3] = (__bf16)pa2.w;
        whi[4] = (__bf16)pa3.x; whi[5] = (__bf16)pa3.y;
        whi[6] = (__bf16)pa3.z; whi[7] = (__bf16)pa3.w;
        *reinterpret_cast<bf16x8*>(Ab + woff0) = wlo;
        *reinterpret_cast<bf16x8*>(Ab + woff1) = whi;
        *reinterpret_cast<uint4*>(Bb + woff0) = pb0;
        *reinterpret_cast<uint4*>(Bb + woff1) = pb1;
        // issue next step's loads (in flight across barrier + MFMA phase)
        if (t < 23) {
            const float*  ap = aG + (t + 1) * 64;
            const __bf16* bp = bG + (t + 1) * 64;
            pa0 = *reinterpret_cast<const f32x4*>(ap);
            pa1 = *reinterpret_cast<const f32x4*>(ap + 4);
            pa2 = *reinterpret_cast<const f32x4*>(ap + 8);
            pa3 = *reinterpret_cast<const f32x4*>(ap + 12);
            pb0 = *reinterpret_cast<const uint4*>(bp);
            pb1 = *reinterpret_cast<const uint4*>(bp + 8);
        }
        __syncthreads();
        #pragma unroll
        for (int ks = 0; ks < 2; ++ks) {
            const int koff = (ks * 64 + lg * 16) ^ rsw;
            const bf16x8 am0 = *reinterpret_cast<const bf16x8*>(Ab + rowA0 + koff);
            const bf16x8 am1 = *reinterpret_cast<const bf16x8*>(Ab + rowA0 + 2048 + koff);
            const bf16x8 bn0 = *reinterpret_cast<const bf16x8*>(Bb + rowB0 + koff);
            const bf16x8 bn1 = *reinterpret_cast<const bf16x8*>(Bb + rowB0 + 2048 + koff);
            acc00 = __builtin_amdgcn_mfma_f32_16x16x32_bf16(am0, bn0, acc00, 0, 0, 0);
            acc01 = __builtin_amdgcn_mfma_f32_16x16x32_bf16(am0, bn1, acc01, 0, 0, 0);
            acc10 = __builtin_amdgcn_mfma_f32_16x16x32_bf16(am1, bn0, acc10, 0, 0, 0);
            acc11 = __builtin_amdgcn_mfma_f32_16x16x32_bf16(am1, bn1, acc11, 0, 0, 0);
        }
        __syncthreads();
    }

    // epilogue: atomic accumulate partials. D: col=lane&15, row=4*(lane>>4)+r
    float* ob = out + ((size_t)s * NA + a0 + m0 + lg * 4) * OD + n0 + lr;
    #pragma unroll
    for (int r = 0; r < 4; ++r) {
        atomicAdd(ob + (size_t)(r) * OD,            acc00[r]);
        atomicAdd(ob + (size_t)(r) * OD + 16,       acc01[r]);
        atomicAdd(ob + (size_t)(16 + r) * OD,       acc10[r]);
        atomicAdd(ob + (size_t)(16 + r) * OD + 16,  acc11[r]);
    }
}

extern "C" void kernel_launch(void* const* d_in, const int* in_sizes, int n_in,
                              void* d_out, int out_size, void* d_ws, size_t ws_size,
                              hipStream_t stream) {
    const float* node = (const float*)d_in[0];
    const float* conn = (const float*)d_in[1];
    const float* bond = (const float*)d_in[2];
    const float* W    = (const float*)d_in[3];
    float* out = (float*)d_out;
    __bf16* gt = (__bf16*)d_ws;    // 32*64*6144 bf16 = 25.2 MB

    k_prep<<<dim3(NS * 64), dim3(256), 0, stream>>>(node, W, gt);
    k_init<<<dim3(NS * NA / 4), dim3(256), 0, stream>>>(bond, W, out);
    k_main<<<dim3(NS * 32), dim3(256), 0, stream>>>(conn, gt, out);
}